// Round 4
// baseline (242.783 us; speedup 1.0000x reference)
//
#include <hip/hip_runtime.h>
#include <hip/hip_fp16.h>

// Problem constants: B=4, N=2048, D=1024, H=16, DH=64.  M = B*N = 8192.

typedef _Float16 half8 __attribute__((ext_vector_type(8)));
typedef float f32x4 __attribute__((ext_vector_type(4)));
typedef float f32x16 __attribute__((ext_vector_type(16)));
typedef unsigned int u32x4 __attribute__((ext_vector_type(4)));

#define DEV __device__ __forceinline__
#define MFMA16(a, b, c) __builtin_amdgcn_mfma_f32_16x16x32_f16(a, b, c, 0, 0, 0)
#define MFMA32(a, b, c) __builtin_amdgcn_mfma_f32_32x32x16_f16(a, b, c, 0, 0, 0)

DEV void gload_lds16(const void* g, void* l) {
  __builtin_amdgcn_global_load_lds(
      (const __attribute__((address_space(1))) void*)g,
      (__attribute__((address_space(3))) void*)l, 16, 0, 0);
}

// ---------------- cast f32 -> f16 (8 elems / thread) ----------------
__global__ __launch_bounds__(256) void cast_f32h(const float* __restrict__ s,
                                                 __half* __restrict__ d, int n8) {
  int i = blockIdx.x * 256 + threadIdx.x;
  if (i >= n8) return;
  const float4* sp = (const float4*)s + (size_t)i * 2;
  float4 a = sp[0], b = sp[1];
  half8 h;
  h[0] = (_Float16)a.x; h[1] = (_Float16)a.y; h[2] = (_Float16)a.z; h[3] = (_Float16)a.w;
  h[4] = (_Float16)b.x; h[5] = (_Float16)b.y; h[6] = (_Float16)b.z; h[7] = (_Float16)b.w;
  *((half8*)d + i) = h;
}

// ---------------- 128x128 GEMM, NT (both operands K-contiguous), K=1024 ----
// MODE 0: QKV epilogue (q scaled by 8*log2e so attention works in exp2 domain)
// MODE 1: proj epilogue -> f32 out + bias
template <int MODE>
__global__ __launch_bounds__(256) void gemm128(
    const __half* __restrict__ A, const __half* __restrict__ Bm,
    const float* __restrict__ b0, const float* __restrict__ b1,
    const float* __restrict__ b2, __half* __restrict__ oh,
    float* __restrict__ of) {
  const int m0 = blockIdx.y * 128;
  const int n0 = blockIdx.x * 128;
  const int tid = threadIdx.x;
  const int w = tid >> 6, lane = tid & 63;
  const int lr = lane & 15, lq = lane >> 4;
  const int wr = w >> 1, wc = w & 1;

  __shared__ alignas(16) __half As[128 * 64];
  __shared__ alignas(16) __half Bs[128 * 64];

  f32x4 acc[4][4] = {};

  const int arow = lane >> 3;
  const int acol = (lane & 7) * 8;
  const __half* Agp = A + ((size_t)m0 + w * 32 + arow) * 1024 + acol;
  const __half* Bgp = Bm + ((size_t)n0 + w * 32 + arow) * 1024 + acol;

  for (int kt = 0; kt < 16; ++kt) {
#pragma unroll
    for (int j = 0; j < 4; ++j) {
      gload_lds16(Agp + j * 8192 + kt * 64, As + (w * 4 + j) * 512);
      gload_lds16(Bgp + j * 8192 + kt * 64, Bs + (w * 4 + j) * 512);
    }
    __syncthreads();
#pragma unroll
    for (int s = 0; s < 2; ++s) {
      half8 af[4], bf[4];
#pragma unroll
      for (int i = 0; i < 4; ++i) {
        af[i] = *(const half8*)(As + (wr * 64 + i * 16 + lr) * 64 + s * 32 + lq * 8);
        bf[i] = *(const half8*)(Bs + (wc * 64 + i * 16 + lr) * 64 + s * 32 + lq * 8);
      }
#pragma unroll
      for (int mi = 0; mi < 4; ++mi)
#pragma unroll
        for (int ni = 0; ni < 4; ++ni)
          acc[mi][ni] = MFMA16(af[mi], bf[ni], acc[mi][ni]);
    }
    __syncthreads();
  }

  if (MODE == 0) {
#pragma unroll
    for (int ni = 0; ni < 4; ++ni) {
      int col = n0 + wc * 64 + ni * 16 + lr;
      int t = col >> 10, e = col & 1023;
      const float* bb = (t == 0) ? b0 : ((t == 1) ? b1 : b2);
      float bias = bb[e];
      // q pre-scale: sqrt(DH) * log2(e) so softmax runs in exp2 domain
      float scale = (t == 0) ? 11.541560327111707f : 1.0f;
      int hh = e >> 6, dh = e & 63;
      __half* base = oh + (size_t)t * 8388608 + dh;
#pragma unroll
      for (int mi = 0; mi < 4; ++mi)
#pragma unroll
        for (int r = 0; r < 4; ++r) {
          int row = m0 + wr * 64 + mi * 16 + lq * 4 + r;
          int b_ = row >> 11, n = row & 2047;
          float v = (acc[mi][ni][r] + bias) * scale;
          base[(((size_t)(b_ * 16 + hh) * 2048 + n) * 64)] = __float2half(v);
        }
    }
  } else {
#pragma unroll
    for (int ni = 0; ni < 4; ++ni) {
      int col = n0 + wc * 64 + ni * 16 + lr;
      float bias = b0[col];
#pragma unroll
      for (int mi = 0; mi < 4; ++mi)
#pragma unroll
        for (int r = 0; r < 4; ++r) {
          int row = m0 + wr * 64 + mi * 16 + lq * 4 + r;
          of[(size_t)row * 1024 + col] = acc[mi][ni][r] + bias;
        }
    }
  }
}

// ---------------- V transpose: [bh][2048][64] -> [bh][64][2048] ------------
__global__ __launch_bounds__(256) void vtrans(const __half* __restrict__ V,
                                              __half* __restrict__ Vt) {
  const int bh = blockIdx.y;
  const int n0 = blockIdx.x * 64;
  const int tid = threadIdx.x;
  __shared__ alignas(16) __half t[64][80];

  const __half* src = V + ((size_t)bh * 2048 + n0) * 64;
#pragma unroll
  for (int j = 0; j < 2; ++j) {
    int lin = (tid + j * 256) * 8;
    int r = lin >> 6, c = lin & 63;
    *(half8*)&t[r][c] = *(const half8*)(src + (size_t)r * 64 + c);
  }
  __syncthreads();
  __half* dst = Vt + (size_t)bh * 64 * 2048 + n0;
#pragma unroll
  for (int j = 0; j < 2; ++j) {
    int lin = (tid + j * 256) * 8;
    int dh = lin >> 6, c = lin & 63;
    half8 v;
#pragma unroll
    for (int i = 0; i < 8; ++i) v[i] = *(_Float16*)&t[c + i][dh];
    *(half8*)(dst + (size_t)dh * 2048 + c) = v;
  }
}

// ---------------- causal flash attention, 32x32 swapped-operand form -------
// Q,K: [bh][2048][64] f16 (Q pre-scaled by 8*log2e).  Vt: [bh][64][2048] f16.
// O: [b][n][h*64+dh] f16.
// Block: 512 thr = 8 waves. Waves 0-3 ("A", qsub=w&3) take even kv tiles,
// waves 4-7 ("B") take odd kv tiles; both cover q rows q0+qsub*32..+31.
// S^T = mfma32(Kfrag, Qfrag): lane owns q = q0+qsub*32+(lane&31).
// P built in-register (pack + shfl_xor(32)); O^T = mfma32(Vtfrag, Pfrag) so
// the online rescale is a per-lane scalar.  4-slot LDS ring via
// global_load_lds (pre-swizzled source), counted vmcnt(4).  A/B merged
// through LDS at q-tile end.  Pair p handles q-tiles p and 15-p.
// XCD swizzle: 1-D grid, bh = id&63 -> all 8 pair-blocks of a bh on one XCD.
// launch_bounds(512,2): 256-reg budget -- round-3's (512,4) capped at 128
// and spilled ~280 MB/dispatch to scratch.
__global__ __launch_bounds__(512, 2) void attn256(const __half* __restrict__ Q,
                                                  const __half* __restrict__ K,
                                                  const __half* __restrict__ Vt,
                                                  __half* __restrict__ O) {
  const int wg = blockIdx.x;
  const int bh = wg & 63;        // id mod 8 == bh mod 8 -> same XCD per bh
  const int pair = wg >> 6;
  const int b = bh >> 4, h = bh & 15;
  const int tid = threadIdx.x;
  const int w = tid >> 6, lane = tid & 63;
  const int c = lane & 31, hi = lane >> 5;
  const int qsub = w & 3, grp = w >> 2;

  __shared__ alignas(16) char smem[65536];
  __half* KsH = (__half*)smem;                    // 4 slots x 4096 halves
  __half* VsH = (__half*)(smem + 32768);          // 4 slots x 4096 halves

  const __half* Kb = K + (size_t)bh * 131072;
  const __half* Vb = Vt + (size_t)bh * 131072;

  // staging: linear LDS dest (tid*16B); source column pre-swizzled so that
  // LDS holds byte = (row*128 + col*2) ^ ((row&7)<<4)
  const int srow = tid >> 3;
  const int scolh = ((tid & 7) ^ (srow & 7)) * 8;

#define STAGE(t)                                                               \
  do {                                                                         \
    gload_lds16(Kb + (size_t)((t)*64 + srow) * 64 + scolh,                     \
                KsH + ((t)&3) * 4096 + tid * 8);                               \
    gload_lds16(Vb + (size_t)srow * 2048 + (t)*64 + scolh,                     \
                VsH + ((t)&3) * 4096 + tid * 8);                               \
  } while (0)

  for (int half_ = 0; half_ < 2; ++half_) {
    const int qt = half_ ? (15 - pair) : pair;
    const int q0 = qt * 128;
    const int T = 2 * qt + 2;      // kv tiles (even)
    const int S = qt + 1;          // super-iterations
    const int rmin = q0 + qsub * 32;
    const int myq = rmin + c;

    // Q B-fragments: B[col=q=c][k = ksl*16 + hi*8 + j]
    const __half* Qp = Q + ((size_t)bh * 2048 + rmin + c) * 64;
    half8 qf[4];
#pragma unroll
    for (int i = 0; i < 4; ++i) qf[i] = *(const half8*)(Qp + i * 16 + hi * 8);

    f32x16 accA = {0,0,0,0,0,0,0,0,0,0,0,0,0,0,0,0};  // O^T, dh 0-31
    f32x16 accB = {0,0,0,0,0,0,0,0,0,0,0,0,0,0,0,0};  // O^T, dh 32-63
    float m = -INFINITY, lp = 0.f;

    const int npro = T < 4 ? T : 4;
    for (int t = 0; t < npro; ++t) STAGE(t);

    for (int s = 0; s < S; ++s) {
      if (s == S - 1) asm volatile("s_waitcnt vmcnt(0)" ::: "memory");
      else            asm volatile("s_waitcnt vmcnt(4)" ::: "memory");
      __builtin_amdgcn_s_barrier();
      asm volatile("" ::: "memory");

      const int t = 2 * s + grp;
      const int k0 = t * 64;
      if (k0 <= rmin + 31) {
        const char* Kc = smem + (t & 3) * 8192;
        const char* Vc = smem + 32768 + (t & 3) * 8192;
        // --- S^T = K * Q^T : out row = key (reg pattern), col = q = c
        f32x16 sA = {0,0,0,0,0,0,0,0,0,0,0,0,0,0,0,0};
        f32x16 sB = {0,0,0,0,0,0,0,0,0,0,0,0,0,0,0,0};
        __builtin_amdgcn_s_setprio(1);
#pragma unroll
        for (int ksl = 0; ksl < 4; ++ksl) {
          half8 ka = *(const half8*)(Kc + ((c * 128 + ksl * 32 + hi * 16) ^ ((c & 7) << 4)));
          half8 kb = *(const half8*)(Kc + (((c + 32) * 128 + ksl * 32 + hi * 16) ^ ((c & 7) << 4)));
          sA = MFMA32(ka, qf[ksl], sA);
          sB = MFMA32(kb, qf[ksl], sB);
        }
        __builtin_amdgcn_s_setprio(0);

        // --- causal mask: key(r,hi) = (r&3) + 8*(r>>2) + 4*hi
        if (k0 + 63 > rmin) {
#pragma unroll
          for (int r = 0; r < 16; ++r) {
            int key = k0 + (r & 3) + 8 * (r >> 2) + 4 * hi;
            if (key > myq) sA[r] = -INFINITY;
            if (key + 32 > myq) sB[r] = -INFINITY;
          }
        }

        // --- row max: 31 fmax + 1 cross-lane (lane^32 holds other 32 keys)
        float rm = sA[0];
#pragma unroll
        for (int r = 1; r < 16; ++r) rm = fmaxf(rm, sA[r]);
#pragma unroll
        for (int r = 0; r < 16; ++r) rm = fmaxf(rm, sB[r]);
        rm = fmaxf(rm, __shfl_xor(rm, 32));
        if (!__all(rm <= m)) {
          float mn = fmaxf(m, rm);
          float al = __builtin_amdgcn_exp2f(m - mn);
          m = mn;
          lp *= al;
#pragma unroll
          for (int r = 0; r < 16; ++r) { accA[r] *= al; accB[r] *= al; }
        }

        // --- per 32-key chunk: exp2 IN PLACE, pack to f16, build PV B-frags
        auto chunk = [&](f32x16& sv, const int kc, const char* Vcl) {
          float l0 = 0.f, l1 = 0.f, l2 = 0.f, l3 = 0.f;
#pragma unroll
          for (int r = 0; r < 16; r += 4) {
            sv[r] = __builtin_amdgcn_exp2f(sv[r] - m);
            sv[r + 1] = __builtin_amdgcn_exp2f(sv[r + 1] - m);
            sv[r + 2] = __builtin_amdgcn_exp2f(sv[r + 2] - m);
            sv[r + 3] = __builtin_amdgcn_exp2f(sv[r + 3] - m);
            l0 += sv[r]; l1 += sv[r + 1]; l2 += sv[r + 2]; l3 += sv[r + 3];
          }
          lp += (l0 + l1) + (l2 + l3);
          unsigned pk[8], xk[8];
#pragma unroll
          for (int i = 0; i < 8; ++i) {
            __half2 h2 = __floats2half2_rn(sv[2 * i], sv[2 * i + 1]);
            pk[i] = *(unsigned*)&h2;
            xk[i] = __shfl_xor(pk[i], 32);
          }
#pragma unroll
          for (int ksl = 0; ksl < 2; ++ksl) {
            // B-frag needs P[key = ks*16 + hi*8 + j][q=c]
            const int i0 = 2 * hi + 4 * ksl;
            u32x4 fu;
            fu[0] = hi ? xk[i0] : pk[i0];
            fu[1] = hi ? xk[i0 + 1] : pk[i0 + 1];
            fu[2] = hi ? pk[i0] : xk[i0];
            fu[3] = hi ? pk[i0 + 1] : xk[i0 + 1];
            half8 pf = *(half8*)&fu;
            const int ks = kc * 2 + ksl;
            half8 va = *(const half8*)(Vcl + ((c * 128 + ks * 32 + hi * 16) ^ ((c & 7) << 4)));
            half8 vb = *(const half8*)(Vcl + (((c + 32) * 128 + ks * 32 + hi * 16) ^ ((c & 7) << 4)));
            __builtin_amdgcn_s_setprio(1);
            accA = MFMA32(va, pf, accA);
            accB = MFMA32(vb, pf, accB);
            __builtin_amdgcn_s_setprio(0);
          }
        };
        chunk(sA, 0, Vc);
        chunk(sB, 1, Vc);
      }
      asm volatile("s_waitcnt lgkmcnt(0)" ::: "memory");
      __builtin_amdgcn_s_barrier();
      asm volatile("" ::: "memory");
      if (2 * s + 4 < T) STAGE(2 * s + 4);
      if (2 * s + 5 < T) STAGE(2 * s + 5);
    }

    // ---- merge groups A/B and write out -------------------------------
    float lt = lp + __shfl_xor(lp, 32);  // both key-halves of this group

    if (grp == 1) {  // dump (O^T regs, m, l) to LDS
      float* dst = (float*)(smem + (w - 4) * 9216 + lane * 144);
#pragma unroll
      for (int i = 0; i < 4; ++i) {
        f32x4 t4;
        t4[0] = accA[4 * i]; t4[1] = accA[4 * i + 1];
        t4[2] = accA[4 * i + 2]; t4[3] = accA[4 * i + 3];
        *(f32x4*)(dst + 4 * i) = t4;
      }
#pragma unroll
      for (int i = 0; i < 4; ++i) {
        f32x4 t4;
        t4[0] = accB[4 * i]; t4[1] = accB[4 * i + 1];
        t4[2] = accB[4 * i + 2]; t4[3] = accB[4 * i + 3];
        *(f32x4*)(dst + 16 + 4 * i) = t4;
      }
      dst[32] = m;
      dst[33] = lt;
    }
    __syncthreads();
    if (grp == 0) {
      const float* src = (const float*)(smem + w * 9216 + lane * 144);
      float oB[32];
#pragma unroll
      for (int i = 0; i < 8; ++i) {
        f32x4 t4 = *(const f32x4*)(src + 4 * i);
        oB[4 * i] = t4[0]; oB[4 * i + 1] = t4[1];
        oB[4 * i + 2] = t4[2]; oB[4 * i + 3] = t4[3];
      }
      float mB = src[32], lB = src[33];
      float mf = fmaxf(m, mB);
      float aA = __builtin_amdgcn_exp2f(m - mf);
      float aB = __builtin_amdgcn_exp2f(mB - mf);
      float inv = 1.f / (lt * aA + lB * aB);
      aA *= inv; aB *= inv;

      // combined+normalized O^T -> LDS transpose buffer [32 q][36 u32 cols]
      unsigned* tr = (unsigned*)(smem + 36864 + w * 4608);
#pragma unroll
      for (int dt = 0; dt < 2; ++dt)
#pragma unroll
        for (int i = 0; i < 8; ++i) {
          float v0 = (dt ? accB[2 * i] : accA[2 * i]) * aA + oB[dt * 16 + 2 * i] * aB;
          float v1 = (dt ? accB[2 * i + 1] : accA[2 * i + 1]) * aA + oB[dt * 16 + 2 * i + 1] * aB;
          __half2 h2 = __floats2half2_rn(v0, v1);
          // dh pair base = 2(i&1) + 8(i>>1) + 4hi + 32dt  -> u32 col:
          int idx = (i & 1) + 4 * (i >> 1) + 2 * hi + 16 * dt;
          tr[c * 36 + idx] = *(unsigned*)&h2;
        }
      asm volatile("s_waitcnt lgkmcnt(0)" ::: "memory");
      __builtin_amdgcn_sched_barrier(0);
      const int rq = lane >> 1, ch = lane & 1;
      __half* Op = O + ((size_t)b * 2048 + q0 + qsub * 32 + rq) * 1024 + h * 64 + ch * 32;
#pragma unroll
      for (int ii = 0; ii < 4; ++ii) {
        u32x4 u = *(const u32x4*)(tr + rq * 36 + ch * 16 + 4 * ii);
        *(u32x4*)(Op + ii * 8) = u;
      }
    }
    __syncthreads();
  }
#undef STAGE
}

// ---------------- launch ---------------------------------------------------
extern "C" void kernel_launch(void* const* d_in, const int* in_sizes, int n_in,
                              void* d_out, int out_size, void* d_ws,
                              size_t ws_size, hipStream_t stream) {
  const float* x = (const float*)d_in[0];
  const float* Wq = (const float*)d_in[1];
  const float* bq = (const float*)d_in[2];
  const float* Wk = (const float*)d_in[3];
  const float* bk = (const float*)d_in[4];
  const float* Wv = (const float*)d_in[5];
  const float* bv = (const float*)d_in[6];
  const float* Wp = (const float*)d_in[7];
  const float* bp = (const float*)d_in[8];

  // workspace layout (bytes)
  char* ws = (char*)d_ws;
  const size_t XB = 0;                       // 16777216
  const size_t WQKV = XB + 16777216;         // 6291456
  const size_t WPB = WQKV + 6291456;         // 2097152
  const size_t QKV = WPB + 2097152;          // 50331648
  const size_t VT = QKV + 50331648;          // 16777216
  const size_t OB = VT + 16777216;           // 16777216  (~88 MiB)

  __half* xb = (__half*)(ws + XB);
  __half* wqkv = (__half*)(ws + WQKV);
  __half* wpb = (__half*)(ws + WPB);
  __half* qkv = (__half*)(ws + QKV);
  __half* vt = (__half*)(ws + VT);
  __half* ob = (__half*)(ws + OB);

  cast_f32h<<<4096, 256, 0, stream>>>(x, xb, 1048576);
  cast_f32h<<<512, 256, 0, stream>>>(Wq, wqkv, 131072);
  cast_f32h<<<512, 256, 0, stream>>>(Wk, wqkv + 1048576, 131072);
  cast_f32h<<<512, 256, 0, stream>>>(Wv, wqkv + 2097152, 131072);
  cast_f32h<<<512, 256, 0, stream>>>(Wp, wpb, 131072);

  // QKV: M=8192, N=3072
  gemm128<0><<<dim3(24, 64), 256, 0, stream>>>(xb, wqkv, bq, bk, bv, qkv, nullptr);
  // V -> V^T per head
  vtrans<<<dim3(32, 64), 256, 0, stream>>>(qkv + 2 * 8388608, vt);
  // attention (causal-balanced pairs, 2-group kv split, XCD-swizzled)
  attn256<<<dim3(512), 512, 0, stream>>>(qkv, qkv + 8388608, vt, ob);
  // proj: M=8192, N=1024, f32 out + bias
  gemm128<1><<<dim3(8, 64), 256, 0, stream>>>(ob, wpb, bp, nullptr, nullptr,
                                              nullptr, (float*)d_out);
}

// Round 5
// 219.859 us; speedup vs baseline: 1.1043x; 1.1043x over previous
//
#include <hip/hip_runtime.h>
#include <hip/hip_fp16.h>

// Problem constants: B=4, N=2048, D=1024, H=16, DH=64.  M = B*N = 8192.

typedef _Float16 half8 __attribute__((ext_vector_type(8)));
typedef _Float16 half4 __attribute__((ext_vector_type(4)));
typedef float f32x4 __attribute__((ext_vector_type(4)));

#define DEV __device__ __forceinline__
#define MFMA16(a, b, c) __builtin_amdgcn_mfma_f32_16x16x32_f16(a, b, c, 0, 0, 0)

DEV void gload_lds16(const void* g, void* l) {
  __builtin_amdgcn_global_load_lds(
      (const __attribute__((address_space(1))) void*)g,
      (__attribute__((address_space(3))) void*)l, 16, 0, 0);
}

// ---------------- cast f32 -> f16 (8 elems / thread) ----------------
__global__ __launch_bounds__(256) void cast_f32h(const float* __restrict__ s,
                                                 __half* __restrict__ d, int n8) {
  int i = blockIdx.x * 256 + threadIdx.x;
  if (i >= n8) return;
  const float4* sp = (const float4*)s + (size_t)i * 2;
  float4 a = sp[0], b = sp[1];
  half8 h;
  h[0] = (_Float16)a.x; h[1] = (_Float16)a.y; h[2] = (_Float16)a.z; h[3] = (_Float16)a.w;
  h[4] = (_Float16)b.x; h[5] = (_Float16)b.y; h[6] = (_Float16)b.z; h[7] = (_Float16)b.w;
  *((half8*)d + i) = h;
}

// ---------------- 128x128 GEMM, NT (both operands K-contiguous), K=1024 ----
// MODE 0: QKV epilogue. q scaled by 8*log2e (exp2-domain softmax), k plain,
//         v written DIRECTLY TRANSPOSED to vt[bh][dh][n] (8B half4 stores).
// MODE 1: proj epilogue -> f32 out + bias.
template <int MODE>
__global__ __launch_bounds__(256) void gemm128(
    const __half* __restrict__ A, const __half* __restrict__ Bm,
    const float* __restrict__ b0, const float* __restrict__ b1,
    const float* __restrict__ b2, __half* __restrict__ oh,
    __half* __restrict__ vtp, float* __restrict__ of) {
  const int m0 = blockIdx.y * 128;
  const int n0 = blockIdx.x * 128;
  const int tid = threadIdx.x;
  const int w = tid >> 6, lane = tid & 63;
  const int lr = lane & 15, lq = lane >> 4;
  const int wr = w >> 1, wc = w & 1;

  __shared__ alignas(16) __half As[128 * 64];
  __shared__ alignas(16) __half Bs[128 * 64];

  f32x4 acc[4][4] = {};

  const int arow = lane >> 3;
  const int acol = (lane & 7) * 8;
  const __half* Agp = A + ((size_t)m0 + w * 32 + arow) * 1024 + acol;
  const __half* Bgp = Bm + ((size_t)n0 + w * 32 + arow) * 1024 + acol;

  for (int kt = 0; kt < 16; ++kt) {
#pragma unroll
    for (int j = 0; j < 4; ++j) {
      gload_lds16(Agp + j * 8192 + kt * 64, As + (w * 4 + j) * 512);
      gload_lds16(Bgp + j * 8192 + kt * 64, Bs + (w * 4 + j) * 512);
    }
    __syncthreads();
#pragma unroll
    for (int s = 0; s < 2; ++s) {
      half8 af[4], bf[4];
#pragma unroll
      for (int i = 0; i < 4; ++i) {
        af[i] = *(const half8*)(As + (wr * 64 + i * 16 + lr) * 64 + s * 32 + lq * 8);
        bf[i] = *(const half8*)(Bs + (wc * 64 + i * 16 + lr) * 64 + s * 32 + lq * 8);
      }
#pragma unroll
      for (int mi = 0; mi < 4; ++mi)
#pragma unroll
        for (int ni = 0; ni < 4; ++ni)
          acc[mi][ni] = MFMA16(af[mi], bf[ni], acc[mi][ni]);
    }
    __syncthreads();
  }

  if (MODE == 0) {
#pragma unroll
    for (int ni = 0; ni < 4; ++ni) {
      int col = n0 + wc * 64 + ni * 16 + lr;
      int t = col >> 10, e = col & 1023;
      const float* bb = (t == 0) ? b0 : ((t == 1) ? b1 : b2);
      float bias = bb[e];
      int hh = e >> 6, dh = e & 63;
      if (t == 2) {
        // V: transposed write vt[(b*16+hh)][dh][n], 4 consecutive n = 8B
#pragma unroll
        for (int mi = 0; mi < 4; ++mi) {
          int row = m0 + wr * 64 + mi * 16 + lq * 4;
          int b_ = row >> 11, n = row & 2047;
          half4 h;
#pragma unroll
          for (int r = 0; r < 4; ++r) h[r] = (_Float16)(acc[mi][ni][r] + bias);
          *(half4*)(vtp + (size_t)(b_ * 16 + hh) * 131072 + (size_t)dh * 2048 + n) = h;
        }
      } else {
        // q pre-scale: sqrt(DH)*log2(e) -> softmax runs in exp2 domain
        float scale = (t == 0) ? 11.541560327111707f : 1.0f;
        __half* base = oh + (size_t)t * 8388608 + dh;
#pragma unroll
        for (int mi = 0; mi < 4; ++mi)
#pragma unroll
          for (int r = 0; r < 4; ++r) {
            int row = m0 + wr * 64 + mi * 16 + lq * 4 + r;
            int b_ = row >> 11, n = row & 2047;
            float v = (acc[mi][ni][r] + bias) * scale;
            base[(((size_t)(b_ * 16 + hh) * 2048 + n) * 64)] = __float2half(v);
          }
      }
    }
  } else {
#pragma unroll
    for (int ni = 0; ni < 4; ++ni) {
      int col = n0 + wc * 64 + ni * 16 + lr;
      float bias = b0[col];
#pragma unroll
      for (int mi = 0; mi < 4; ++mi)
#pragma unroll
        for (int r = 0; r < 4; ++r) {
          int row = m0 + wr * 64 + mi * 16 + lq * 4 + r;
          of[(size_t)row * 1024 + col] = acc[mi][ni][r] + bias;
        }
    }
  }
}

// ---------------- causal flash attention, 128-q blocks, 8 waves ------------
// Q,K: [bh][2048][64] f16 (Q pre-scaled by 8*log2e).  Vt: [bh][64][2048] f16.
// O: [b][n][h*64+dh] f16 (= [8192][1024], ready for proj GEMM).
// 1-D grid 512: bh = wg&63 (wg mod 8 == bh mod 8 -> all 8 pair-blocks of a
// bh on one XCD; round 4 measured FETCH 146->44 MB with this mapping).
// Block = 512 thr = 8 waves; 16 q-rows/wave. Pair p: q-tiles p and 15-p.
// K/V double-buffered global_load_lds, pre-swizzled source, counted vmcnt(2).
// Softmax: exp2-domain, defer-max THR=8 (T13), setprio around MFMA (T5).
__global__ __launch_bounds__(512, 4) void attn128(const __half* __restrict__ Q,
                                                  const __half* __restrict__ K,
                                                  const __half* __restrict__ Vt,
                                                  __half* __restrict__ O) {
  const int wg = blockIdx.x;
  const int bh = wg & 63;
  const int pair = wg >> 6;
  const int b = bh >> 4, h = bh & 15;
  const int tid = threadIdx.x;
  const int w = tid >> 6, lane = tid & 63;
  const int lr = lane & 15, lq = lane >> 4;

  __shared__ alignas(16) __half Ks[2][64 * 64];
  __shared__ alignas(16) __half Vs[2][64 * 64];
  __shared__ alignas(16) __half Ps[8][16 * 64];

  const __half* Kb = K + (size_t)bh * 131072;
  const __half* Vb = Vt + (size_t)bh * 131072;

  // staging: LDS slot = w*1024 + lane*16 bytes (linear); source pre-swizzled
  // so LDS holds byte = (r*128 + c*2) ^ ((r&7)<<4)
  const int srow = lane >> 3;
  const int scol = ((lane & 7) ^ srow) * 8;

  for (int half_ = 0; half_ < 2; ++half_) {
    const int qt = half_ ? (15 - pair) : pair;
    const int q0 = qt * 128;
    const int ktend = 2 * qt + 2;
    const int rmin = q0 + w * 16;

    const __half* Qp = Q + ((size_t)bh * 2048 + q0 + w * 16) * 64;
    half8 qf0 = *(const half8*)(Qp + lr * 64 + lq * 8);
    half8 qf1 = *(const half8*)(Qp + lr * 64 + 32 + lq * 8);

    f32x4 oacc[4] = {};
    float m_r[4] = {-INFINITY, -INFINITY, -INFINITY, -INFINITY};
    float l_r[4] = {0.f, 0.f, 0.f, 0.f};

    // prologue: stage tile 0 -> buf 0
    gload_lds16(Kb + (size_t)(0 + w * 8 + srow) * 64 + scol, Ks[0] + w * 512);
    gload_lds16(Vb + (size_t)(w * 8 + srow) * 2048 + 0 + scol, Vs[0] + w * 512);
    asm volatile("" ::: "memory");

    for (int kt = 0; kt < ktend; ++kt) {
      const int cur = kt & 1;
      const int k0 = kt * 64;
      if (kt + 1 < ktend) {
        const int kn = k0 + 64;
        gload_lds16(Kb + (size_t)(kn + w * 8 + srow) * 64 + scol,
                    Ks[cur ^ 1] + w * 512);
        gload_lds16(Vb + (size_t)(w * 8 + srow) * 2048 + kn + scol,
                    Vs[cur ^ 1] + w * 512);
        asm volatile("s_waitcnt vmcnt(2)" ::: "memory");
      } else {
        asm volatile("s_waitcnt vmcnt(0)" ::: "memory");
      }
      __builtin_amdgcn_s_barrier();
      asm volatile("" ::: "memory");

      const char* Kc = (const char*)Ks[cur];
      const char* Vc = (const char*)Vs[cur];
      const bool active = (k0 <= rmin + 15);
      if (active) {
        // --- S = Q K^T  (16 q rows x 64 keys per wave)
        f32x4 sacc[4] = {};
        __builtin_amdgcn_s_setprio(1);
#pragma unroll
        for (int nt = 0; nt < 4; ++nt) {
          int row = nt * 16 + lr;
          half8 kb0 = *(const half8*)(Kc + ((row * 128 + lq * 16) ^ ((row & 7) << 4)));
          half8 kb1 = *(const half8*)(Kc + ((row * 128 + 64 + lq * 16) ^ ((row & 7) << 4)));
          sacc[nt] = MFMA16(qf0, kb0, sacc[nt]);
          sacc[nt] = MFMA16(qf1, kb1, sacc[nt]);
        }
        __builtin_amdgcn_s_setprio(0);

        // --- causal mask (diagonal sub-tiles only)
        if (k0 + 63 > rmin) {
#pragma unroll
          for (int nt = 0; nt < 4; ++nt)
#pragma unroll
            for (int rr = 0; rr < 4; ++rr) {
              int colk = k0 + nt * 16 + lr;
              int rowq = rmin + lq * 4 + rr;
              if (colk > rowq) sacc[nt][rr] = -INFINITY;
            }
        }

        // --- online softmax (exp2 domain; S pre-scaled by log2e)
        float mt[4];
#pragma unroll
        for (int rr = 0; rr < 4; ++rr)
          mt[rr] = fmaxf(fmaxf(sacc[0][rr], sacc[1][rr]),
                         fmaxf(sacc[2][rr], sacc[3][rr]));
#pragma unroll
        for (int off = 1; off < 16; off <<= 1)
#pragma unroll
          for (int rr = 0; rr < 4; ++rr) mt[rr] = fmaxf(mt[rr], __shfl_xor(mt[rr], off));

        // defer-max (T13): rescale only if any row grew by > 8 (p <= 2^8)
        bool grow = false;
#pragma unroll
        for (int rr = 0; rr < 4; ++rr) grow = grow || (mt[rr] > m_r[rr] + 8.f);
        if (__any(grow)) {
#pragma unroll
          for (int rr = 0; rr < 4; ++rr) {
            float mn = fmaxf(m_r[rr], mt[rr]);
            float al = __builtin_amdgcn_exp2f(m_r[rr] - mn);
            m_r[rr] = mn;
            l_r[rr] *= al;
#pragma unroll
            for (int dt = 0; dt < 4; ++dt) oacc[dt][rr] *= al;
          }
        }

        float rs[4] = {0.f, 0.f, 0.f, 0.f};
#pragma unroll
        for (int nt = 0; nt < 4; ++nt)
#pragma unroll
          for (int rr = 0; rr < 4; ++rr) {
            float p = __builtin_amdgcn_exp2f(sacc[nt][rr] - m_r[rr]);
            rs[rr] += p;
            int prow = lq * 4 + rr, pcol = nt * 16 + lr;
            *(__half*)((char*)Ps[w] + ((prow * 128 + pcol * 2) ^ ((prow & 7) << 4))) =
                __float2half(p);
          }
#pragma unroll
        for (int off = 1; off < 16; off <<= 1)
#pragma unroll
          for (int rr = 0; rr < 4; ++rr) rs[rr] += __shfl_xor(rs[rr], off);
#pragma unroll
        for (int rr = 0; rr < 4; ++rr) l_r[rr] += rs[rr];

        // --- PV: A = P row (k contiguous), B = V^T tile
        half8 pa0 = *(const half8*)((char*)Ps[w] + ((lr * 128 + lq * 16) ^ ((lr & 7) << 4)));
        half8 pa1 = *(const half8*)((char*)Ps[w] + ((lr * 128 + 64 + lq * 16) ^ ((lr & 7) << 4)));
        __builtin_amdgcn_s_setprio(1);
#pragma unroll
        for (int dt = 0; dt < 4; ++dt) {
          int row = dt * 16 + lr;
          half8 vb0 = *(const half8*)(Vc + ((row * 128 + lq * 16) ^ ((row & 7) << 4)));
          half8 vb1 = *(const half8*)(Vc + ((row * 128 + 64 + lq * 16) ^ ((row & 7) << 4)));
          oacc[dt] = MFMA16(pa0, vb0, oacc[dt]);
          oacc[dt] = MFMA16(pa1, vb1, oacc[dt]);
        }
        __builtin_amdgcn_s_setprio(0);
      }
      asm volatile("s_waitcnt lgkmcnt(0)" ::: "memory");
      __builtin_amdgcn_s_barrier();
      asm volatile("" ::: "memory");
    }

    float inv[4];
#pragma unroll
    for (int rr = 0; rr < 4; ++rr) inv[rr] = 1.0f / l_r[rr];
    __half* Op = O + ((size_t)b * 2048 + q0 + w * 16) * 1024 + h * 64;
#pragma unroll
    for (int dt = 0; dt < 4; ++dt)
#pragma unroll
      for (int rr = 0; rr < 4; ++rr)
        Op[(size_t)(lq * 4 + rr) * 1024 + dt * 16 + lr] =
            __float2half(oacc[dt][rr] * inv[rr]);
  }
}

// ---------------- launch ---------------------------------------------------
extern "C" void kernel_launch(void* const* d_in, const int* in_sizes, int n_in,
                              void* d_out, int out_size, void* d_ws,
                              size_t ws_size, hipStream_t stream) {
  const float* x = (const float*)d_in[0];
  const float* Wq = (const float*)d_in[1];
  const float* bq = (const float*)d_in[2];
  const float* Wk = (const float*)d_in[3];
  const float* bk = (const float*)d_in[4];
  const float* Wv = (const float*)d_in[5];
  const float* bv = (const float*)d_in[6];
  const float* Wp = (const float*)d_in[7];
  const float* bp = (const float*)d_in[8];

  // workspace layout (bytes)
  char* ws = (char*)d_ws;
  const size_t XB = 0;                       // 16777216
  const size_t WQKV = XB + 16777216;         // 6291456
  const size_t WPB = WQKV + 6291456;         // 2097152
  const size_t QKV = WPB + 2097152;          // 50331648 (v slot unused)
  const size_t VT = QKV + 50331648;          // 16777216
  const size_t OB = VT + 16777216;           // 16777216  (~109 MiB)

  __half* xb = (__half*)(ws + XB);
  __half* wqkv = (__half*)(ws + WQKV);
  __half* wpb = (__half*)(ws + WPB);
  __half* qkv = (__half*)(ws + QKV);
  __half* vt = (__half*)(ws + VT);
  __half* ob = (__half*)(ws + OB);

  cast_f32h<<<4096, 256, 0, stream>>>(x, xb, 1048576);
  cast_f32h<<<512, 256, 0, stream>>>(Wq, wqkv, 131072);
  cast_f32h<<<512, 256, 0, stream>>>(Wk, wqkv + 1048576, 131072);
  cast_f32h<<<512, 256, 0, stream>>>(Wv, wqkv + 2097152, 131072);
  cast_f32h<<<512, 256, 0, stream>>>(Wp, wpb, 131072);

  // QKV: M=8192, N=3072 (V written transposed into vt; vtrans kernel gone)
  gemm128<0><<<dim3(24, 64), 256, 0, stream>>>(xb, wqkv, bq, bk, bv, qkv, vt,
                                               nullptr);
  // attention (causal-balanced pairs, XCD-swizzled 1-D grid)
  attn128<<<dim3(512), 512, 0, stream>>>(qkv, qkv + 8388608, vt, ob);
  // proj: M=8192, N=1024, f32 out + bias
  gemm128<1><<<dim3(8, 64), 256, 0, stream>>>(ob, wpb, bp, nullptr, nullptr,
                                              nullptr, nullptr, (float*)d_out);
}

// Round 6
// 191.202 us; speedup vs baseline: 1.2698x; 1.1499x over previous
//
#include <hip/hip_runtime.h>
#include <hip/hip_fp16.h>

// Problem constants: B=4, N=2048, D=1024, H=16, DH=64.  M = B*N = 8192.

typedef _Float16 half8 __attribute__((ext_vector_type(8)));
typedef _Float16 half4 __attribute__((ext_vector_type(4)));
typedef float f32x4 __attribute__((ext_vector_type(4)));
typedef unsigned int u32x4 __attribute__((ext_vector_type(4)));

#define DEV __device__ __forceinline__
#define MFMA16(a, b, c) __builtin_amdgcn_mfma_f32_16x16x32_f16(a, b, c, 0, 0, 0)

DEV void gload_lds16(const void* g, void* l) {
  __builtin_amdgcn_global_load_lds(
      (const __attribute__((address_space(1))) void*)g,
      (__attribute__((address_space(3))) void*)l, 16, 0, 0);
}

// ---------------- cast f32 -> f16 (8 elems / thread) ----------------
__global__ __launch_bounds__(256) void cast_f32h(const float* __restrict__ s,
                                                 __half* __restrict__ d, int n8) {
  int i = blockIdx.x * 256 + threadIdx.x;
  if (i >= n8) return;
  const float4* sp = (const float4*)s + (size_t)i * 2;
  float4 a = sp[0], b = sp[1];
  half8 h;
  h[0] = (_Float16)a.x; h[1] = (_Float16)a.y; h[2] = (_Float16)a.z; h[3] = (_Float16)a.w;
  h[4] = (_Float16)b.x; h[5] = (_Float16)b.y; h[6] = (_Float16)b.z; h[7] = (_Float16)b.w;
  *((half8*)d + i) = h;
}

// ---------------- 128x128 GEMM, NT (both operands K-contiguous), K=1024 ----
// MODE 0: QKV epilogue. q scaled by 8*log2e (exp2-domain softmax), k plain,
//         v written DIRECTLY TRANSPOSED to vt[bh][dh][n] (8B half4 stores).
// MODE 1: proj epilogue -> f32 out + bias.
template <int MODE>
__global__ __launch_bounds__(256) void gemm128(
    const __half* __restrict__ A, const __half* __restrict__ Bm,
    const float* __restrict__ b0, const float* __restrict__ b1,
    const float* __restrict__ b2, __half* __restrict__ oh,
    __half* __restrict__ vtp, float* __restrict__ of) {
  const int m0 = blockIdx.y * 128;
  const int n0 = blockIdx.x * 128;
  const int tid = threadIdx.x;
  const int w = tid >> 6, lane = tid & 63;
  const int lr = lane & 15, lq = lane >> 4;
  const int wr = w >> 1, wc = w & 1;

  __shared__ alignas(16) __half As[128 * 64];
  __shared__ alignas(16) __half Bs[128 * 64];

  f32x4 acc[4][4] = {};

  const int arow = lane >> 3;
  const int acol = (lane & 7) * 8;
  const __half* Agp = A + ((size_t)m0 + w * 32 + arow) * 1024 + acol;
  const __half* Bgp = Bm + ((size_t)n0 + w * 32 + arow) * 1024 + acol;

  for (int kt = 0; kt < 16; ++kt) {
#pragma unroll
    for (int j = 0; j < 4; ++j) {
      gload_lds16(Agp + j * 8192 + kt * 64, As + (w * 4 + j) * 512);
      gload_lds16(Bgp + j * 8192 + kt * 64, Bs + (w * 4 + j) * 512);
    }
    __syncthreads();
#pragma unroll
    for (int s = 0; s < 2; ++s) {
      half8 af[4], bf[4];
#pragma unroll
      for (int i = 0; i < 4; ++i) {
        af[i] = *(const half8*)(As + (wr * 64 + i * 16 + lr) * 64 + s * 32 + lq * 8);
        bf[i] = *(const half8*)(Bs + (wc * 64 + i * 16 + lr) * 64 + s * 32 + lq * 8);
      }
#pragma unroll
      for (int mi = 0; mi < 4; ++mi)
#pragma unroll
        for (int ni = 0; ni < 4; ++ni)
          acc[mi][ni] = MFMA16(af[mi], bf[ni], acc[mi][ni]);
    }
    __syncthreads();
  }

  if (MODE == 0) {
#pragma unroll
    for (int ni = 0; ni < 4; ++ni) {
      int col = n0 + wc * 64 + ni * 16 + lr;
      int t = col >> 10, e = col & 1023;
      const float* bb = (t == 0) ? b0 : ((t == 1) ? b1 : b2);
      float bias = bb[e];
      int hh = e >> 6, dh = e & 63;
      if (t == 2) {
        // V: transposed write vt[(b*16+hh)][dh][n], 4 consecutive n = 8B
#pragma unroll
        for (int mi = 0; mi < 4; ++mi) {
          int row = m0 + wr * 64 + mi * 16 + lq * 4;
          int b_ = row >> 11, n = row & 2047;
          half4 h;
#pragma unroll
          for (int r = 0; r < 4; ++r) h[r] = (_Float16)(acc[mi][ni][r] + bias);
          *(half4*)(vtp + (size_t)(b_ * 16 + hh) * 131072 + (size_t)dh * 2048 + n) = h;
        }
      } else {
        // q pre-scale: sqrt(DH)*log2(e) -> softmax runs in exp2 domain
        float scale = (t == 0) ? 11.541560327111707f : 1.0f;
        __half* base = oh + (size_t)t * 8388608 + dh;
#pragma unroll
        for (int mi = 0; mi < 4; ++mi)
#pragma unroll
          for (int r = 0; r < 4; ++r) {
            int row = m0 + wr * 64 + mi * 16 + lq * 4 + r;
            int b_ = row >> 11, n = row & 2047;
            float v = (acc[mi][ni][r] + bias) * scale;
            base[(((size_t)(b_ * 16 + hh) * 2048 + n) * 64)] = __float2half(v);
          }
      }
    }
  } else {
#pragma unroll
    for (int ni = 0; ni < 4; ++ni) {
      int col = n0 + wc * 64 + ni * 16 + lr;
      float bias = b0[col];
#pragma unroll
      for (int mi = 0; mi < 4; ++mi)
#pragma unroll
        for (int r = 0; r < 4; ++r) {
          int row = m0 + wr * 64 + mi * 16 + lq * 4 + r;
          of[(size_t)row * 1024 + col] = acc[mi][ni][r] + bias;
        }
    }
  }
}

// ---------------- causal flash attention, swapped-operand QK^T -------------
// Q,K: [bh][2048][64] f16 (Q pre-scaled by 8*log2e).  Vt: [bh][64][2048] f16.
// O: [b][n][h*64+dh] f16.
// S^T = MFMA16(K_frag, Q_frag): same LDS reads / Q regs as the normal form,
// but each lane owns ONE query (col = lane&15) with 16 key-values in regs
// (key = k0 + nt*16 + lq*4 + r, m89 C-layout).  Softmax: 15-op reg tree +
// 2 shfl_xor (16,32).  P packed in-register (cvt_pk) and redistributed to
// the PV A-fragment with 16 bpermute + 8 selects; no P LDS round-trip.
// PV / V-reads / epilogue unchanged; 1/l broadcast by 4 epilogue shfl.
// 1-D grid 512: bh = wg&63 (XCD locality).  Pair p: q-tiles p and 15-p.
// K/V double-buffered global_load_lds, pre-swizzled source, counted vmcnt(2).
__global__ __launch_bounds__(512, 4) void attn128(const __half* __restrict__ Q,
                                                  const __half* __restrict__ K,
                                                  const __half* __restrict__ Vt,
                                                  __half* __restrict__ O) {
  const int wg = blockIdx.x;
  const int bh = wg & 63;
  const int pair = wg >> 6;
  const int b = bh >> 4, h = bh & 15;
  const int tid = threadIdx.x;
  const int w = tid >> 6, lane = tid & 63;
  const int lr = lane & 15, lq = lane >> 4;
  const int hi = lane >> 5;
  // exchange source lanes: sA = lr + 32*(lq&1), sB = sA + 16
  const int sA = (lane & 15) | ((lane & 16) << 1);
  const int sB = sA + 16;

  __shared__ alignas(16) __half Ks[2][4096];
  __shared__ alignas(16) __half Vs[2][4096];

  const __half* Kb = K + (size_t)bh * 131072;
  const __half* Vb = Vt + (size_t)bh * 131072;

  // staging: LDS slot = w*1024 + lane*16 bytes (linear); source pre-swizzled
  // so LDS holds byte = (r*128 + c*2) ^ ((r&7)<<4)
  const int srow = lane >> 3;
  const int scol = ((lane & 7) ^ srow) * 8;

  for (int half_ = 0; half_ < 2; ++half_) {
    const int qt = half_ ? (15 - pair) : pair;
    const int q0 = qt * 128;
    const int ktend = 2 * qt + 2;
    const int rmin = q0 + w * 16;
    const int myq = rmin + lr;  // this lane's query row (softmax owner)

    const __half* Qp = Q + ((size_t)bh * 2048 + q0 + w * 16) * 64;
    half8 qf0 = *(const half8*)(Qp + lr * 64 + lq * 8);
    half8 qf1 = *(const half8*)(Qp + lr * 64 + 32 + lq * 8);

    f32x4 oacc[4] = {};
    float m = -INFINITY, l = 0.f;

    // prologue: stage tile 0 -> buf 0
    gload_lds16(Kb + (size_t)(0 + w * 8 + srow) * 64 + scol, Ks[0] + w * 512);
    gload_lds16(Vb + (size_t)(w * 8 + srow) * 2048 + 0 + scol, Vs[0] + w * 512);
    asm volatile("" ::: "memory");

    for (int kt = 0; kt < ktend; ++kt) {
      const int cur = kt & 1;
      const int k0 = kt * 64;
      if (kt + 1 < ktend) {
        const int kn = k0 + 64;
        gload_lds16(Kb + (size_t)(kn + w * 8 + srow) * 64 + scol,
                    Ks[cur ^ 1] + w * 512);
        gload_lds16(Vb + (size_t)(w * 8 + srow) * 2048 + kn + scol,
                    Vs[cur ^ 1] + w * 512);
        asm volatile("s_waitcnt vmcnt(2)" ::: "memory");
      } else {
        asm volatile("s_waitcnt vmcnt(0)" ::: "memory");
      }
      __builtin_amdgcn_s_barrier();
      asm volatile("" ::: "memory");

      const char* Kc = (const char*)Ks[cur];
      const char* Vc = (const char*)Vs[cur];
      const bool active = (k0 <= rmin + 15);
      if (active) {
        // --- S^T = K Q^T: lane owns q = myq; key = k0 + nt*16 + lq*4 + r
        f32x4 sacc[4] = {};
        __builtin_amdgcn_s_setprio(1);
#pragma unroll
        for (int nt = 0; nt < 4; ++nt) {
          int row = nt * 16 + lr;
          half8 kb0 = *(const half8*)(Kc + ((row * 128 + lq * 16) ^ ((row & 7) << 4)));
          half8 kb1 = *(const half8*)(Kc + ((row * 128 + 64 + lq * 16) ^ ((row & 7) << 4)));
          sacc[nt] = MFMA16(kb0, qf0, sacc[nt]);
          sacc[nt] = MFMA16(kb1, qf1, sacc[nt]);
        }
        __builtin_amdgcn_s_setprio(0);

        // --- causal mask (diagonal sub-tiles only)
        if (k0 + 63 > rmin) {
#pragma unroll
          for (int nt = 0; nt < 4; ++nt)
#pragma unroll
            for (int r = 0; r < 4; ++r) {
              int key = k0 + nt * 16 + lq * 4 + r;
              if (key > myq) sacc[nt][r] = -INFINITY;
            }
        }

        // --- row max: in-register tree + 2 cross-group shfl
        float rm = fmaxf(fmaxf(fmaxf(sacc[0][0], sacc[0][1]),
                               fmaxf(sacc[0][2], sacc[0][3])),
                         fmaxf(fmaxf(sacc[1][0], sacc[1][1]),
                               fmaxf(sacc[1][2], sacc[1][3])));
        rm = fmaxf(rm, fmaxf(fmaxf(fmaxf(sacc[2][0], sacc[2][1]),
                                   fmaxf(sacc[2][2], sacc[2][3])),
                             fmaxf(fmaxf(sacc[3][0], sacc[3][1]),
                                   fmaxf(sacc[3][2], sacc[3][3]))));
        rm = fmaxf(rm, __shfl_xor(rm, 16));
        rm = fmaxf(rm, __shfl_xor(rm, 32));

        // defer-max (T13): rescale only if some row grew by > 8
        if (__any(rm > m + 8.f)) {
          float mn = fmaxf(m, rm);
          float al = __builtin_amdgcn_exp2f(m - mn);
          m = mn;
          l *= al;
          float al4[4];
#pragma unroll
          for (int r = 0; r < 4; ++r) al4[r] = __shfl(al, lq * 4 + r);
#pragma unroll
          for (int dt = 0; dt < 4; ++dt)
#pragma unroll
            for (int r = 0; r < 4; ++r) oacc[dt][r] *= al4[r];
        }

        // --- exp2 in place + per-lane sum + cross-group sum
        float ps = 0.f;
#pragma unroll
        for (int nt = 0; nt < 4; ++nt) {
          float p0 = __builtin_amdgcn_exp2f(sacc[nt][0] - m);
          float p1 = __builtin_amdgcn_exp2f(sacc[nt][1] - m);
          float p2 = __builtin_amdgcn_exp2f(sacc[nt][2] - m);
          float p3 = __builtin_amdgcn_exp2f(sacc[nt][3] - m);
          sacc[nt][0] = p0; sacc[nt][1] = p1;
          sacc[nt][2] = p2; sacc[nt][3] = p3;
          ps += (p0 + p1) + (p2 + p3);
        }
        ps += __shfl_xor(ps, 16);
        ps += __shfl_xor(ps, 32);
        l += ps;

        // --- pack P to f16 pairs: ph[2*nt+c] = (p[nt][2c], p[nt][2c+1])
        unsigned ph[8];
#pragma unroll
        for (int nt = 0; nt < 4; ++nt) {
          __half2 a = __floats2half2_rn(sacc[nt][0], sacc[nt][1]);
          __half2 bq_ = __floats2half2_rn(sacc[nt][2], sacc[nt][3]);
          ph[2 * nt] = *(unsigned*)&a;
          ph[2 * nt + 1] = *(unsigned*)&bq_;
        }

        // --- redistribute into PV A-fragments (keys = k-slots):
        // pa0 u32[jj]: keys lq*8+2jj,+2jj+1; tile-select by hi; src sA/sB
        u32x4 fa, fb;
        {
          unsigned t0, t1;
          t0 = __shfl((int)ph[0], sA); t1 = __shfl((int)ph[2], sA);
          fa[0] = hi ? t1 : t0;
          t0 = __shfl((int)ph[1], sA); t1 = __shfl((int)ph[3], sA);
          fa[1] = hi ? t1 : t0;
          t0 = __shfl((int)ph[0], sB); t1 = __shfl((int)ph[2], sB);
          fa[2] = hi ? t1 : t0;
          t0 = __shfl((int)ph[1], sB); t1 = __shfl((int)ph[3], sB);
          fa[3] = hi ? t1 : t0;
          t0 = __shfl((int)ph[4], sA); t1 = __shfl((int)ph[6], sA);
          fb[0] = hi ? t1 : t0;
          t0 = __shfl((int)ph[5], sA); t1 = __shfl((int)ph[7], sA);
          fb[1] = hi ? t1 : t0;
          t0 = __shfl((int)ph[4], sB); t1 = __shfl((int)ph[6], sB);
          fb[2] = hi ? t1 : t0;
          t0 = __shfl((int)ph[5], sB); t1 = __shfl((int)ph[7], sB);
          fb[3] = hi ? t1 : t0;
        }
        half8 pa0 = *(half8*)&fa;
        half8 pa1 = *(half8*)&fb;

        // --- PV: A = P (in-register), B = V^T tile (reads unchanged)
        __builtin_amdgcn_s_setprio(1);
#pragma unroll
        for (int dt = 0; dt < 4; ++dt) {
          int row = dt * 16 + lr;
          half8 vb0 = *(const half8*)(Vc + ((row * 128 + lq * 16) ^ ((row & 7) << 4)));
          half8 vb1 = *(const half8*)(Vc + ((row * 128 + 64 + lq * 16) ^ ((row & 7) << 4)));
          oacc[dt] = MFMA16(pa0, vb0, oacc[dt]);
          oacc[dt] = MFMA16(pa1, vb1, oacc[dt]);
        }
        __builtin_amdgcn_s_setprio(0);
      }
      asm volatile("s_waitcnt lgkmcnt(0)" ::: "memory");
      __builtin_amdgcn_s_barrier();
      asm volatile("" ::: "memory");
    }

    // epilogue: broadcast 1/l from softmax-owner lanes to accumulator rows
    float linv = 1.0f / l;
    float inv4[4];
#pragma unroll
    for (int r = 0; r < 4; ++r) inv4[r] = __shfl(linv, lq * 4 + r);
    __half* Op = O + ((size_t)b * 2048 + q0 + w * 16) * 1024 + h * 64;
#pragma unroll
    for (int dt = 0; dt < 4; ++dt)
#pragma unroll
      for (int r = 0; r < 4; ++r)
        Op[(size_t)(lq * 4 + r) * 1024 + dt * 16 + lr] =
            __float2half(oacc[dt][r] * inv4[r]);
  }
}

// ---------------- launch ---------------------------------------------------
extern "C" void kernel_launch(void* const* d_in, const int* in_sizes, int n_in,
                              void* d_out, int out_size, void* d_ws,
                              size_t ws_size, hipStream_t stream) {
  const float* x = (const float*)d_in[0];
  const float* Wq = (const float*)d_in[1];
  const float* bq = (const float*)d_in[2];
  const float* Wk = (const float*)d_in[3];
  const float* bk = (const float*)d_in[4];
  const float* Wv = (const float*)d_in[5];
  const float* bv = (const float*)d_in[6];
  const float* Wp = (const float*)d_in[7];
  const float* bp = (const float*)d_in[8];

  // workspace layout (bytes)
  char* ws = (char*)d_ws;
  const size_t XB = 0;                       // 16777216
  const size_t WQKV = XB + 16777216;         // 6291456
  const size_t WPB = WQKV + 6291456;         // 2097152
  const size_t QKV = WPB + 2097152;          // 50331648 (v slot unused)
  const size_t VT = QKV + 50331648;          // 16777216
  const size_t OB = VT + 16777216;           // 16777216  (~109 MiB)

  __half* xb = (__half*)(ws + XB);
  __half* wqkv = (__half*)(ws + WQKV);
  __half* wpb = (__half*)(ws + WPB);
  __half* qkv = (__half*)(ws + QKV);
  __half* vt = (__half*)(ws + VT);
  __half* ob = (__half*)(ws + OB);

  cast_f32h<<<4096, 256, 0, stream>>>(x, xb, 1048576);
  cast_f32h<<<512, 256, 0, stream>>>(Wq, wqkv, 131072);
  cast_f32h<<<512, 256, 0, stream>>>(Wk, wqkv + 1048576, 131072);
  cast_f32h<<<512, 256, 0, stream>>>(Wv, wqkv + 2097152, 131072);
  cast_f32h<<<512, 256, 0, stream>>>(Wp, wpb, 131072);

  // QKV: M=8192, N=3072 (V written transposed into vt)
  gemm128<0><<<dim3(24, 64), 256, 0, stream>>>(xb, wqkv, bq, bk, bv, qkv, vt,
                                               nullptr);
  // attention (causal-balanced pairs, XCD-swizzled 1-D grid)
  attn128<<<dim3(512), 512, 0, stream>>>(qkv, qkv + 8388608, vt, ob);
  // proj: M=8192, N=1024, f32 out + bias
  gemm128<1><<<dim3(8, 64), 256, 0, stream>>>(ob, wpb, bp, nullptr, nullptr,
                                              nullptr, nullptr, (float*)d_out);
}

// Round 7
// 184.390 us; speedup vs baseline: 1.3167x; 1.0369x over previous
//
#include <hip/hip_runtime.h>
#include <hip/hip_fp16.h>

// Problem constants: B=4, N=2048, D=1024, H=16, DH=64.  M = B*N = 8192.

typedef _Float16 half8 __attribute__((ext_vector_type(8)));
typedef _Float16 half4 __attribute__((ext_vector_type(4)));
typedef float f32x4 __attribute__((ext_vector_type(4)));
typedef unsigned int u32x4 __attribute__((ext_vector_type(4)));

#define DEV __device__ __forceinline__
#define MFMA16(a, b, c) __builtin_amdgcn_mfma_f32_16x16x32_f16(a, b, c, 0, 0, 0)

DEV void gload_lds16(const void* g, void* l) {
  __builtin_amdgcn_global_load_lds(
      (const __attribute__((address_space(1))) void*)g,
      (__attribute__((address_space(3))) void*)l, 16, 0, 0);
}

// ---------------- fused cast f32 -> f16 (x + 4 weight matrices) ------------
// index space (half8 units): [x:1048576][Wq:131072][Wk][Wv][Wp]
__global__ __launch_bounds__(256) void cast_all(
    const float* __restrict__ x, const float* __restrict__ Wq,
    const float* __restrict__ Wk, const float* __restrict__ Wv,
    const float* __restrict__ Wp, __half* __restrict__ xb,
    __half* __restrict__ wqkv, __half* __restrict__ wpb) {
  int i = blockIdx.x * 256 + threadIdx.x;
  const float* s;
  __half* d;
  int j;
  if (i < 1048576) {
    s = x; d = xb; j = i;
  } else {
    int k = i - 1048576;
    int sel = k >> 17;
    j = k & 131071;
    s = (sel == 0) ? Wq : (sel == 1) ? Wk : (sel == 2) ? Wv : Wp;
    d = (sel == 3) ? wpb : (wqkv + sel * 1048576);
  }
  const float4* sp = (const float4*)s + (size_t)j * 2;
  float4 a = sp[0], b = sp[1];
  half8 h;
  h[0] = (_Float16)a.x; h[1] = (_Float16)a.y; h[2] = (_Float16)a.z; h[3] = (_Float16)a.w;
  h[4] = (_Float16)b.x; h[5] = (_Float16)b.y; h[6] = (_Float16)b.z; h[7] = (_Float16)b.w;
  *((half8*)d + j) = h;
}

// ---------------- 128x128 GEMM, NT (both operands K-contiguous), K=1024 ----
// MODE 0: QKV epilogue. q scaled by 8*log2e (exp2-domain softmax), k plain,
//         v written DIRECTLY TRANSPOSED to vt[bh][dh][n] (8B half4 stores).
// MODE 1: proj epilogue -> f32 out + bias.
template <int MODE>
__global__ __launch_bounds__(256) void gemm128(
    const __half* __restrict__ A, const __half* __restrict__ Bm,
    const float* __restrict__ b0, const float* __restrict__ b1,
    const float* __restrict__ b2, __half* __restrict__ oh,
    __half* __restrict__ vtp, float* __restrict__ of) {
  const int m0 = blockIdx.y * 128;
  const int n0 = blockIdx.x * 128;
  const int tid = threadIdx.x;
  const int w = tid >> 6, lane = tid & 63;
  const int lr = lane & 15, lq = lane >> 4;
  const int wr = w >> 1, wc = w & 1;

  __shared__ alignas(16) __half As[128 * 64];
  __shared__ alignas(16) __half Bs[128 * 64];

  f32x4 acc[4][4] = {};

  const int arow = lane >> 3;
  const int acol = (lane & 7) * 8;
  const __half* Agp = A + ((size_t)m0 + w * 32 + arow) * 1024 + acol;
  const __half* Bgp = Bm + ((size_t)n0 + w * 32 + arow) * 1024 + acol;

  for (int kt = 0; kt < 16; ++kt) {
#pragma unroll
    for (int j = 0; j < 4; ++j) {
      gload_lds16(Agp + j * 8192 + kt * 64, As + (w * 4 + j) * 512);
      gload_lds16(Bgp + j * 8192 + kt * 64, Bs + (w * 4 + j) * 512);
    }
    __syncthreads();
#pragma unroll
    for (int s = 0; s < 2; ++s) {
      half8 af[4], bf[4];
#pragma unroll
      for (int i = 0; i < 4; ++i) {
        af[i] = *(const half8*)(As + (wr * 64 + i * 16 + lr) * 64 + s * 32 + lq * 8);
        bf[i] = *(const half8*)(Bs + (wc * 64 + i * 16 + lr) * 64 + s * 32 + lq * 8);
      }
#pragma unroll
      for (int mi = 0; mi < 4; ++mi)
#pragma unroll
        for (int ni = 0; ni < 4; ++ni)
          acc[mi][ni] = MFMA16(af[mi], bf[ni], acc[mi][ni]);
    }
    __syncthreads();
  }

  if (MODE == 0) {
#pragma unroll
    for (int ni = 0; ni < 4; ++ni) {
      int col = n0 + wc * 64 + ni * 16 + lr;
      int t = col >> 10, e = col & 1023;
      const float* bb = (t == 0) ? b0 : ((t == 1) ? b1 : b2);
      float bias = bb[e];
      int hh = e >> 6, dh = e & 63;
      if (t == 2) {
        // V: transposed write vt[(b*16+hh)][dh][n], 4 consecutive n = 8B
#pragma unroll
        for (int mi = 0; mi < 4; ++mi) {
          int row = m0 + wr * 64 + mi * 16 + lq * 4;
          int b_ = row >> 11, n = row & 2047;
          half4 h;
#pragma unroll
          for (int r = 0; r < 4; ++r) h[r] = (_Float16)(acc[mi][ni][r] + bias);
          *(half4*)(vtp + (size_t)(b_ * 16 + hh) * 131072 + (size_t)dh * 2048 + n) = h;
        }
      } else {
        // q pre-scale: sqrt(DH)*log2(e) -> softmax runs in exp2 domain
        float scale = (t == 0) ? 11.541560327111707f : 1.0f;
        __half* base = oh + (size_t)t * 8388608 + dh;
#pragma unroll
        for (int mi = 0; mi < 4; ++mi)
#pragma unroll
          for (int r = 0; r < 4; ++r) {
            int row = m0 + wr * 64 + mi * 16 + lq * 4 + r;
            int b_ = row >> 11, n = row & 2047;
            float v = (acc[mi][ni][r] + bias) * scale;
            base[(((size_t)(b_ * 16 + hh) * 2048 + n) * 64)] = __float2half(v);
          }
      }
    }
  } else {
#pragma unroll
    for (int ni = 0; ni < 4; ++ni) {
      int col = n0 + wc * 64 + ni * 16 + lr;
      float bias = b0[col];
#pragma unroll
      for (int mi = 0; mi < 4; ++mi)
#pragma unroll
        for (int r = 0; r < 4; ++r) {
          int row = m0 + wr * 64 + mi * 16 + lq * 4 + r;
          of[(size_t)row * 1024 + col] = acc[mi][ni][r] + bias;
        }
    }
  }
}

// ---------------- causal flash attention, swapped-operand QK^T -------------
// Q,K: [bh][2048][64] f16 (Q pre-scaled by 8*log2e).  Vt: [bh][64][2048] f16.
// O: [b][n][h*64+dh] f16.
// S^T = MFMA16(K_frag, Q_frag): each lane owns ONE query (col = lane&15)
// with 16 key-values in regs (key = k0 + nt*16 + lq*4 + r, m89 C-layout).
// Softmax: 15-op reg tree + 2 shfl_xor; P packed in-register and
// redistributed to the PV A-fragment with 16 bpermute + 8 selects.
// Grid: 1024 blocks = one q-tile each (4 blocks/CU, full wave slots).
// bh = wg&63 keeps XCD affinity (r4: FETCH 146->27 MB); qt = 15-(wg>>6)
// dispatches longest blocks first (descending-work tail fix).
// K/V double-buffered global_load_lds, pre-swizzled source, counted vmcnt(2).
__global__ __launch_bounds__(512, 4) void attn128(const __half* __restrict__ Q,
                                                  const __half* __restrict__ K,
                                                  const __half* __restrict__ Vt,
                                                  __half* __restrict__ O) {
  const int wg = blockIdx.x;
  const int bh = wg & 63;
  const int qt = 15 - (wg >> 6);
  const int b = bh >> 4, h = bh & 15;
  const int tid = threadIdx.x;
  const int w = tid >> 6, lane = tid & 63;
  const int lr = lane & 15, lq = lane >> 4;
  const int hi = lane >> 5;
  // exchange source lanes: sA = lr + 32*(lq&1), sB = sA + 16
  const int sA = (lane & 15) | ((lane & 16) << 1);
  const int sB = sA + 16;

  __shared__ alignas(16) __half Ks[2][4096];
  __shared__ alignas(16) __half Vs[2][4096];

  const __half* Kb = K + (size_t)bh * 131072;
  const __half* Vb = Vt + (size_t)bh * 131072;

  // staging: LDS slot = w*1024 + lane*16 bytes (linear); source pre-swizzled
  // so LDS holds byte = (r*128 + c*2) ^ ((r&7)<<4)
  const int srow = lane >> 3;
  const int scol = ((lane & 7) ^ srow) * 8;

  const int q0 = qt * 128;
  const int ktend = 2 * qt + 2;
  const int rmin = q0 + w * 16;
  const int myq = rmin + lr;  // this lane's query row (softmax owner)

  const __half* Qp = Q + ((size_t)bh * 2048 + q0 + w * 16) * 64;
  half8 qf0 = *(const half8*)(Qp + lr * 64 + lq * 8);
  half8 qf1 = *(const half8*)(Qp + lr * 64 + 32 + lq * 8);

  f32x4 oacc[4] = {};
  float m = -INFINITY, l = 0.f;

  // prologue: stage tile 0 -> buf 0
  gload_lds16(Kb + (size_t)(0 + w * 8 + srow) * 64 + scol, Ks[0] + w * 512);
  gload_lds16(Vb + (size_t)(w * 8 + srow) * 2048 + 0 + scol, Vs[0] + w * 512);
  asm volatile("" ::: "memory");

  for (int kt = 0; kt < ktend; ++kt) {
    const int cur = kt & 1;
    const int k0 = kt * 64;
    if (kt + 1 < ktend) {
      const int kn = k0 + 64;
      gload_lds16(Kb + (size_t)(kn + w * 8 + srow) * 64 + scol,
                  Ks[cur ^ 1] + w * 512);
      gload_lds16(Vb + (size_t)(w * 8 + srow) * 2048 + kn + scol,
                  Vs[cur ^ 1] + w * 512);
      asm volatile("s_waitcnt vmcnt(2)" ::: "memory");
    } else {
      asm volatile("s_waitcnt vmcnt(0)" ::: "memory");
    }
    __builtin_amdgcn_s_barrier();
    asm volatile("" ::: "memory");

    const char* Kc = (const char*)Ks[cur];
    const char* Vc = (const char*)Vs[cur];
    const bool active = (k0 <= rmin + 15);
    if (active) {
      // --- S^T = K Q^T: lane owns q = myq; key = k0 + nt*16 + lq*4 + r
      f32x4 sacc[4] = {};
      __builtin_amdgcn_s_setprio(1);
#pragma unroll
      for (int nt = 0; nt < 4; ++nt) {
        int row = nt * 16 + lr;
        half8 kb0 = *(const half8*)(Kc + ((row * 128 + lq * 16) ^ ((row & 7) << 4)));
        half8 kb1 = *(const half8*)(Kc + ((row * 128 + 64 + lq * 16) ^ ((row & 7) << 4)));
        sacc[nt] = MFMA16(kb0, qf0, sacc[nt]);
        sacc[nt] = MFMA16(kb1, qf1, sacc[nt]);
      }
      __builtin_amdgcn_s_setprio(0);

      // --- causal mask (diagonal sub-tiles only)
      if (k0 + 63 > rmin) {
#pragma unroll
        for (int nt = 0; nt < 4; ++nt)
#pragma unroll
          for (int r = 0; r < 4; ++r) {
            int key = k0 + nt * 16 + lq * 4 + r;
            if (key > myq) sacc[nt][r] = -INFINITY;
          }
      }

      // --- row max: in-register tree + 2 cross-group shfl
      float rm = fmaxf(fmaxf(fmaxf(sacc[0][0], sacc[0][1]),
                             fmaxf(sacc[0][2], sacc[0][3])),
                       fmaxf(fmaxf(sacc[1][0], sacc[1][1]),
                             fmaxf(sacc[1][2], sacc[1][3])));
      rm = fmaxf(rm, fmaxf(fmaxf(fmaxf(sacc[2][0], sacc[2][1]),
                                 fmaxf(sacc[2][2], sacc[2][3])),
                           fmaxf(fmaxf(sacc[3][0], sacc[3][1]),
                                 fmaxf(sacc[3][2], sacc[3][3]))));
      rm = fmaxf(rm, __shfl_xor(rm, 16));
      rm = fmaxf(rm, __shfl_xor(rm, 32));

      // defer-max (T13): rescale only if some row grew by > 8
      if (__any(rm > m + 8.f)) {
        float mn = fmaxf(m, rm);
        float al = __builtin_amdgcn_exp2f(m - mn);
        m = mn;
        l *= al;
        float al4[4];
#pragma unroll
        for (int r = 0; r < 4; ++r) al4[r] = __shfl(al, lq * 4 + r);
#pragma unroll
        for (int dt = 0; dt < 4; ++dt)
#pragma unroll
          for (int r = 0; r < 4; ++r) oacc[dt][r] *= al4[r];
      }

      // --- exp2 in place + per-lane sum + cross-group sum
      float ps = 0.f;
#pragma unroll
      for (int nt = 0; nt < 4; ++nt) {
        float p0 = __builtin_amdgcn_exp2f(sacc[nt][0] - m);
        float p1 = __builtin_amdgcn_exp2f(sacc[nt][1] - m);
        float p2 = __builtin_amdgcn_exp2f(sacc[nt][2] - m);
        float p3 = __builtin_amdgcn_exp2f(sacc[nt][3] - m);
        sacc[nt][0] = p0; sacc[nt][1] = p1;
        sacc[nt][2] = p2; sacc[nt][3] = p3;
        ps += (p0 + p1) + (p2 + p3);
      }
      ps += __shfl_xor(ps, 16);
      ps += __shfl_xor(ps, 32);
      l += ps;

      // --- pack P to f16 pairs: ph[2*nt+c] = (p[nt][2c], p[nt][2c+1])
      unsigned ph[8];
#pragma unroll
      for (int nt = 0; nt < 4; ++nt) {
        __half2 a = __floats2half2_rn(sacc[nt][0], sacc[nt][1]);
        __half2 bq_ = __floats2half2_rn(sacc[nt][2], sacc[nt][3]);
        ph[2 * nt] = *(unsigned*)&a;
        ph[2 * nt + 1] = *(unsigned*)&bq_;
      }

      // --- redistribute into PV A-fragments (keys = k-slots)
      u32x4 fa, fb;
      {
        unsigned t0, t1;
        t0 = __shfl((int)ph[0], sA); t1 = __shfl((int)ph[2], sA);
        fa[0] = hi ? t1 : t0;
        t0 = __shfl((int)ph[1], sA); t1 = __shfl((int)ph[3], sA);
        fa[1] = hi ? t1 : t0;
        t0 = __shfl((int)ph[0], sB); t1 = __shfl((int)ph[2], sB);
        fa[2] = hi ? t1 : t0;
        t0 = __shfl((int)ph[1], sB); t1 = __shfl((int)ph[3], sB);
        fa[3] = hi ? t1 : t0;
        t0 = __shfl((int)ph[4], sA); t1 = __shfl((int)ph[6], sA);
        fb[0] = hi ? t1 : t0;
        t0 = __shfl((int)ph[5], sA); t1 = __shfl((int)ph[7], sA);
        fb[1] = hi ? t1 : t0;
        t0 = __shfl((int)ph[4], sB); t1 = __shfl((int)ph[6], sB);
        fb[2] = hi ? t1 : t0;
        t0 = __shfl((int)ph[5], sB); t1 = __shfl((int)ph[7], sB);
        fb[3] = hi ? t1 : t0;
      }
      half8 pa0 = *(half8*)&fa;
      half8 pa1 = *(half8*)&fb;

      // --- PV: A = P (in-register), B = V^T tile
      __builtin_amdgcn_s_setprio(1);
#pragma unroll
      for (int dt = 0; dt < 4; ++dt) {
        int row = dt * 16 + lr;
        half8 vb0 = *(const half8*)(Vc + ((row * 128 + lq * 16) ^ ((row & 7) << 4)));
        half8 vb1 = *(const half8*)(Vc + ((row * 128 + 64 + lq * 16) ^ ((row & 7) << 4)));
        oacc[dt] = MFMA16(pa0, vb0, oacc[dt]);
        oacc[dt] = MFMA16(pa1, vb1, oacc[dt]);
      }
      __builtin_amdgcn_s_setprio(0);
    }
    asm volatile("s_waitcnt lgkmcnt(0)" ::: "memory");
    __builtin_amdgcn_s_barrier();
    asm volatile("" ::: "memory");
  }

  // epilogue: broadcast 1/l from softmax-owner lanes to accumulator rows
  float linv = 1.0f / l;
  float inv4[4];
#pragma unroll
  for (int r = 0; r < 4; ++r) inv4[r] = __shfl(linv, lq * 4 + r);
  __half* Op = O + ((size_t)b * 2048 + q0 + w * 16) * 1024 + h * 64;
#pragma unroll
  for (int dt = 0; dt < 4; ++dt)
#pragma unroll
    for (int r = 0; r < 4; ++r)
      Op[(size_t)(lq * 4 + r) * 1024 + dt * 16 + lr] =
          __float2half(oacc[dt][r] * inv4[r]);
}

// ---------------- launch ---------------------------------------------------
extern "C" void kernel_launch(void* const* d_in, const int* in_sizes, int n_in,
                              void* d_out, int out_size, void* d_ws,
                              size_t ws_size, hipStream_t stream) {
  const float* x = (const float*)d_in[0];
  const float* Wq = (const float*)d_in[1];
  const float* bq = (const float*)d_in[2];
  const float* Wk = (const float*)d_in[3];
  const float* bk = (const float*)d_in[4];
  const float* Wv = (const float*)d_in[5];
  const float* bv = (const float*)d_in[6];
  const float* Wp = (const float*)d_in[7];
  const float* bp = (const float*)d_in[8];

  // workspace layout (bytes)
  char* ws = (char*)d_ws;
  const size_t XB = 0;                       // 16777216
  const size_t WQKV = XB + 16777216;         // 6291456
  const size_t WPB = WQKV + 6291456;         // 2097152
  const size_t QKV = WPB + 2097152;          // 50331648 (v slot unused)
  const size_t VT = QKV + 50331648;          // 16777216
  const size_t OB = VT + 16777216;           // 16777216  (~109 MiB)

  __half* xb = (__half*)(ws + XB);
  __half* wqkv = (__half*)(ws + WQKV);
  __half* wpb = (__half*)(ws + WPB);
  __half* qkv = (__half*)(ws + QKV);
  __half* vt = (__half*)(ws + VT);
  __half* ob = (__half*)(ws + OB);

  // fused cast: x + Wq + Wk + Wv + Wp (1572864 half8 units)
  cast_all<<<6144, 256, 0, stream>>>(x, Wq, Wk, Wv, Wp, xb, wqkv, wpb);

  // QKV: M=8192, N=3072 (V written transposed into vt)
  gemm128<0><<<dim3(24, 64), 256, 0, stream>>>(xb, wqkv, bq, bk, bv, qkv, vt,
                                               nullptr);
  // attention (1024 blocks: one q-tile each, longest first, XCD-affine)
  attn128<<<dim3(1024), 512, 0, stream>>>(qkv, qkv + 8388608, vt, ob);
  // proj: M=8192, N=1024, f32 out + bias
  gemm128<1><<<dim3(8, 64), 256, 0, stream>>>(ob, wpb, bp, nullptr, nullptr,
                                              nullptr, nullptr, (float*)d_out);
}